// Round 4
// baseline (304.411 us; speedup 1.0000x reference)
//
#include <hip/hip_runtime.h>
#include <stdint.h>

typedef __attribute__((ext_vector_type(8)))  short  short8;
typedef __attribute__((ext_vector_type(8)))  __bf16 bf16x8;
typedef __attribute__((ext_vector_type(16))) float  floatx16;
typedef __attribute__((ext_vector_type(4)))  float  floatx4;
typedef __attribute__((ext_vector_type(4)))  uint32_t uint4v;

union Frag { short8 s; bf16x8 v; uint4v d; };
union FU   { float f; uint32_t u; };

// round-to-nearest-even f32 -> bf16 (setup only)
__device__ __forceinline__ short f2bf(float f) {
    FU x; x.f = f;
    uint32_t r = x.u + 0x7fffu + ((x.u >> 16) & 1u);
    return (short)(r >> 16);
}

// pack two f32 -> bf16x2 dword, round-half-up: 2 adds + 1 v_perm
__device__ __forceinline__ uint32_t pack_bf2(float lo, float hi) {
    FU a, b; a.f = lo; b.f = hi;
    return __builtin_amdgcn_perm(b.u + 0x8000u, a.u + 0x8000u, 0x07060302u);
}

__device__ __forceinline__ float fexp2(float x) { return __builtin_amdgcn_exp2f(x); }
__device__ __forceinline__ float frcp(float x)  { return __builtin_amdgcn_rcpf(x); }
__device__ __forceinline__ float fclamp(float x, float lo, float hi) {
#if __has_builtin(__builtin_amdgcn_fmed3f)
    return __builtin_amdgcn_fmed3f(x, lo, hi);
#else
    return fminf(fmaxf(x, lo), hi);
#endif
}

// y[b] = a0 + sum_k bk[k] * tanh(ck[k,:].z[b,:] + dk[k])
//
// D = mfma_32x32x16_bf16(A=s*ck, B=z, C=s*dk) -> D[node][row] = s*(dot+dk),
// s = 2*log2(e); col(lane&31)=batch row, row(reg-map)=node.
// tanh(t) = 1 - 2/(exp2(s*t)+1); paired denominators:
//   b0/t0 + b1/t1 = (b0*t1 + b1*t0) * rcp(t0*t1)   [48 trans/tile vs 64]
// exp2 arg clamped to +-30 so t0*t1 <= 2^61 (no overflow; tanh err ~2e-9).
//
// R4 DIAGNOSTIC: nrep=4 identical passes per dispatch so the kernel's
// per-dispatch time exceeds the 77us ws-poison fills and surfaces in the
// rocprof top-5 with full counters. Passes write identical values (pure
// function of inputs) -- correctness unaffected. Revert nrep=1 next round.
__global__ __launch_bounds__(256) void mave_kernel(
    const float* __restrict__ z,
    const float* __restrict__ a0,
    const float* __restrict__ bk,
    const float* __restrict__ ck,
    const float* __restrict__ dk,
    float* __restrict__ out,
    int ntiles, int nrep)
{
    const int lane = threadIdx.x & 63;
    const int m    = lane & 31;
    const int g    = lane >> 5;
    const float S  = 2.885390081777927f;  // 2*log2(e)

    // A-operand fragments: rows of s*ck (node = m and m+32), k = g*8+e
    Frag af0, af1;
    {
        const float* c0 = ck + m * 16 + g * 8;
        const float* c1 = c0 + 32 * 16;
        #pragma unroll
        for (int e = 0; e < 8; ++e) {
            af0.s[e] = f2bf(c0[e] * S);
            af1.s[e] = f2bf(c1[e] * S);
        }
    }

    // C-init = s*dk[node]; node map (reg&3)+8*(reg>>2)+4*g.
    // nb = -2*bk[node] packed bf16x2 (lo: nodes 0-31 half, hi: +32 half).
    floatx16 cinit0, cinit1;
    uint32_t nbp[16];
    #pragma unroll
    for (int r = 0; r < 16; ++r) {
        int n = (r & 3) + 8 * (r >> 2) + 4 * g;
        cinit0[r] = S * dk[n];
        cinit1[r] = S * dk[n + 32];
        nbp[r] = pack_bf2(-2.0f * bk[n], -2.0f * bk[n + 32]);
    }

    float base = a0[0];
    for (int k = 0; k < 64; ++k) base += bk[k];

    const int wid = (int)((blockIdx.x * blockDim.x + threadIdx.x) >> 6);
    const int nw  = (int)((gridDim.x * blockDim.x) >> 6);
    const int per  = (ntiles + nw - 1) / nw;       // tiles per wave (8)
    const int tbeg = wid * per;
    const int tend = (tbeg + per < ntiles) ? tbeg + per : ntiles;

    #pragma unroll 1
    for (int rep = 0; rep < nrep; ++rep) {
        if (tbeg >= tend) continue;

        floatx4 a0v, a1v, b0v, b1v;        // double-buffer pipeline regs
        {   // prologue: load tiles tbeg, tbeg+1
            const float* zp = z + (size_t)(tbeg * 32 + m) * 16 + g * 8;
            a0v = *(const floatx4*)zp; a1v = *(const floatx4*)(zp + 4);
            int t1i = (tbeg + 1 < tend) ? tbeg + 1 : tbeg;
            const float* zq = z + (size_t)(t1i * 32 + m) * 16 + g * 8;
            b0v = *(const floatx4*)zq; b1v = *(const floatx4*)(zq + 4);
        }

        #pragma unroll 1
        for (int t = tbeg; t < tend; t += 2) {
            // ---- tile t from buffer A ----
            Frag bfr;
            bfr.d[0] = pack_bf2(a0v.x, a0v.y); bfr.d[1] = pack_bf2(a0v.z, a0v.w);
            bfr.d[2] = pack_bf2(a1v.x, a1v.y); bfr.d[3] = pack_bf2(a1v.z, a1v.w);
            if (t + 2 < tend) {            // refill A (distance-2 prefetch)
                const float* zp = z + (size_t)((t + 2) * 32 + m) * 16 + g * 8;
                a0v = *(const floatx4*)zp; a1v = *(const floatx4*)(zp + 4);
            }
            floatx16 acc0 = __builtin_amdgcn_mfma_f32_32x32x16_bf16(af0.v, bfr.v, cinit0, 0, 0, 0);
            floatx16 acc1 = __builtin_amdgcn_mfma_f32_32x32x16_bf16(af1.v, bfr.v, cinit1, 0, 0, 0);
            float ya = 0.0f, yb = 0.0f;
            #pragma unroll
            for (int r = 0; r < 16; ++r) {
                float e0 = fexp2(fclamp(acc0[r], -30.0f, 30.0f));
                float e1 = fexp2(fclamp(acc1[r], -30.0f, 30.0f));
                float t0 = e0 + 1.0f, t1 = e1 + 1.0f;
                float rd = frcp(t0 * t1);
                FU lo, hi; lo.u = nbp[r] << 16; hi.u = nbp[r] & 0xffff0000u;
                float num = lo.f * t1 + hi.f * t0;
                if (r & 1) yb += num * rd; else ya += num * rd;
            }
            float y = ya + yb;
            y += __shfl_xor(y, 32, 64);
            if (g == 0) out[t * 32 + m] = base + y;

            // ---- tile t+1 from buffer B ----
            if (t + 1 < tend) {
                Frag bf2;
                bf2.d[0] = pack_bf2(b0v.x, b0v.y); bf2.d[1] = pack_bf2(b0v.z, b0v.w);
                bf2.d[2] = pack_bf2(b1v.x, b1v.y); bf2.d[3] = pack_bf2(b1v.z, b1v.w);
                if (t + 3 < tend) {        // refill B
                    const float* zp = z + (size_t)((t + 3) * 32 + m) * 16 + g * 8;
                    b0v = *(const floatx4*)zp; b1v = *(const floatx4*)(zp + 4);
                }
                floatx16 ac0 = __builtin_amdgcn_mfma_f32_32x32x16_bf16(af0.v, bf2.v, cinit0, 0, 0, 0);
                floatx16 ac1 = __builtin_amdgcn_mfma_f32_32x32x16_bf16(af1.v, bf2.v, cinit1, 0, 0, 0);
                float yc = 0.0f, yd = 0.0f;
                #pragma unroll
                for (int r = 0; r < 16; ++r) {
                    float e0 = fexp2(fclamp(ac0[r], -30.0f, 30.0f));
                    float e1 = fexp2(fclamp(ac1[r], -30.0f, 30.0f));
                    float t0 = e0 + 1.0f, t1 = e1 + 1.0f;
                    float rd = frcp(t0 * t1);
                    FU lo, hi; lo.u = nbp[r] << 16; hi.u = nbp[r] & 0xffff0000u;
                    float num = lo.f * t1 + hi.f * t0;
                    if (r & 1) yd += num * rd; else yc += num * rd;
                }
                float y2 = yc + yd;
                y2 += __shfl_xor(y2, 32, 64);
                if (g == 0) out[(t + 1) * 32 + m] = base + y2;
            }
        }
    }
}

extern "C" void kernel_launch(void* const* d_in, const int* in_sizes, int n_in,
                              void* d_out, int out_size, void* d_ws, size_t ws_size,
                              hipStream_t stream) {
    const float* z  = (const float*)d_in[0];
    const float* a0 = (const float*)d_in[1];
    const float* bk = (const float*)d_in[2];
    const float* ck = (const float*)d_in[3];
    const float* dk = (const float*)d_in[4];
    float* out = (float*)d_out;

    const int B      = in_sizes[0] / 16;   // z is [B,16]
    const int ntiles = B / 32;             // 32 batch rows per wave-tile

    dim3 grid(2048), block(256);           // 8192 waves, 8-tile chunk each
    hipLaunchKernelGGL(mave_kernel, grid, block, 0, stream,
                       z, a0, bk, ck, dk, out, ntiles, /*nrep=*/4);
}

// Round 5
// 205.098 us; speedup vs baseline: 1.4842x; 1.4842x over previous
//
#include <hip/hip_runtime.h>
#include <stdint.h>

typedef __attribute__((ext_vector_type(8)))  short  short8;
typedef __attribute__((ext_vector_type(8)))  __bf16 bf16x8;
typedef __attribute__((ext_vector_type(16))) float  floatx16;
typedef __attribute__((ext_vector_type(4)))  float  floatx4;
typedef __attribute__((ext_vector_type(2)))  float  float2v;
typedef __attribute__((ext_vector_type(4)))  uint32_t uint4v;

union Frag { short8 s; bf16x8 v; uint4v d; };
union FU   { float f; uint32_t u; };

// round-to-nearest-even f32 -> bf16 (setup only)
__device__ __forceinline__ short f2bf(float f) {
    FU x; x.f = f;
    uint32_t r = x.u + 0x7fffu + ((x.u >> 16) & 1u);
    return (short)(r >> 16);
}

// pack two f32 -> bf16x2 dword, round-half-up: 2 adds + 1 v_perm
__device__ __forceinline__ uint32_t pack_bf2(float lo, float hi) {
    FU a, b; a.f = lo; b.f = hi;
    return __builtin_amdgcn_perm(b.u + 0x8000u, a.u + 0x8000u, 0x07060302u);
}

__device__ __forceinline__ float fexp2(float x) { return __builtin_amdgcn_exp2f(x); }
__device__ __forceinline__ float frcp(float x)  { return __builtin_amdgcn_rcpf(x); }
__device__ __forceinline__ float fclamp(float x, float lo, float hi) {
#if __has_builtin(__builtin_amdgcn_fmed3f)
    return __builtin_amdgcn_fmed3f(x, lo, hi);
#else
    return fminf(fmaxf(x, lo), hi);
#endif
}

// T = exp2(clamp(arg)) + 1 for the (acc0[r], acc1[r]) pair; the +1 is a
// packed v_pk_add_f32.
__device__ __forceinline__ float2v tpair(float a, float b) {
    float2v t;
    t.x = fexp2(fclamp(a, -30.0f, 30.0f));
    t.y = fexp2(fclamp(b, -30.0f, 30.0f));
    return t + 1.0f;
}

// y[b] = a0 + sum_k bk[k] * tanh(ck[k,:].z[b,:] + dk[k])
//
// D = mfma_32x32x16_bf16(A=s*ck, B=z, C=s*dk) -> D[node][row] = s*(dot+dk),
// s = 2*log2(e); col(lane&31)=batch row, row(reg-map)=node.
// tanh(t) = 1 - 2/(exp2(s*t)+1); 4-way shared denominator:
//   b0/t0+b1/t1+b2/t2+b3/t3 = [(b0t1+b1t0)t2t3 + (b2t3+b3t2)t0t1]
//                             * rcp(t0t1t2t3)
// exp2 arg clamped +-30 => each t<=2^30+1, 4-product <=2^121, no overflow;
// clamp-induced tanh err ~2e-9. Regular VALU runs on float2 (acc0,acc1)
// pairs so clang emits v_pk_{add,mul,fma}_f32 (R4 showed VALUBusy=84% --
// issue-bound, ~1390 VALU-cy/tile; this targets the issue count directly).
__global__ __launch_bounds__(256) void mave_kernel(
    const float* __restrict__ z,
    const float* __restrict__ a0,
    const float* __restrict__ bk,
    const float* __restrict__ ck,
    const float* __restrict__ dk,
    float* __restrict__ out,
    int ntiles)
{
    const int lane = threadIdx.x & 63;
    const int m    = lane & 31;
    const int g    = lane >> 5;
    const float S  = 2.885390081777927f;  // 2*log2(e)

    // A-operand fragments: rows of s*ck (node = m and m+32), k = g*8+e
    Frag af0, af1;
    {
        const float* c0 = ck + m * 16 + g * 8;
        const float* c1 = c0 + 32 * 16;
        #pragma unroll
        for (int e = 0; e < 8; ++e) {
            af0.s[e] = f2bf(c0[e] * S);
            af1.s[e] = f2bf(c1[e] * S);
        }
    }

    // C-init = s*dk[node]; node map (reg&3)+8*(reg>>2)+4*g.
    // nb2[r] = (-2*bk[node], -2*bk[node+32]) pre-unpacked (kills 32
    // unpack ops/tile; VGPR headroom is fine -- we're issue-bound).
    floatx16 cinit0, cinit1;
    float2v nb2[16];
    #pragma unroll
    for (int r = 0; r < 16; ++r) {
        int n = (r & 3) + 8 * (r >> 2) + 4 * g;
        cinit0[r] = S * dk[n];
        cinit1[r] = S * dk[n + 32];
        nb2[r].x = -2.0f * bk[n];
        nb2[r].y = -2.0f * bk[n + 32];
    }

    float base = a0[0];
    for (int k = 0; k < 64; ++k) base += bk[k];

    const int wid = (int)((blockIdx.x * blockDim.x + threadIdx.x) >> 6);
    const int nw  = (int)((gridDim.x * blockDim.x) >> 6);
    const int per  = (ntiles + nw - 1) / nw;       // tiles per wave (8)
    const int tbeg = wid * per;
    const int tend = (tbeg + per < ntiles) ? tbeg + per : ntiles;
    if (tbeg >= tend) return;

    floatx4 a0v, a1v, b0v, b1v;            // double-buffer pipeline regs
    {   // prologue: load tiles tbeg, tbeg+1
        const float* zp = z + (size_t)(tbeg * 32 + m) * 16 + g * 8;
        a0v = *(const floatx4*)zp; a1v = *(const floatx4*)(zp + 4);
        int t1i = (tbeg + 1 < tend) ? tbeg + 1 : tbeg;
        const float* zq = z + (size_t)(t1i * 32 + m) * 16 + g * 8;
        b0v = *(const floatx4*)zq; b1v = *(const floatx4*)(zq + 4);
    }

    #pragma unroll 1
    for (int t = tbeg; t < tend; t += 2) {
        // ---- tile t from buffer A ----
        Frag bfr;
        bfr.d[0] = pack_bf2(a0v.x, a0v.y); bfr.d[1] = pack_bf2(a0v.z, a0v.w);
        bfr.d[2] = pack_bf2(a1v.x, a1v.y); bfr.d[3] = pack_bf2(a1v.z, a1v.w);
        if (t + 2 < tend) {                // refill A (distance-2 prefetch)
            const float* zp = z + (size_t)((t + 2) * 32 + m) * 16 + g * 8;
            a0v = *(const floatx4*)zp; a1v = *(const floatx4*)(zp + 4);
        }
        floatx16 acc0 = __builtin_amdgcn_mfma_f32_32x32x16_bf16(af0.v, bfr.v, cinit0, 0, 0, 0);
        floatx16 acc1 = __builtin_amdgcn_mfma_f32_32x32x16_bf16(af1.v, bfr.v, cinit1, 0, 0, 0);

        float2v Ya = {0.0f, 0.0f}, Yb = {0.0f, 0.0f};
        #pragma unroll
        for (int r = 0; r < 16; r += 4) {
            float2v T0 = tpair(acc0[r+0], acc1[r+0]);
            float2v T1 = tpair(acc0[r+1], acc1[r+1]);
            float2v T2 = tpair(acc0[r+2], acc1[r+2]);
            float2v T3 = tpair(acc0[r+3], acc1[r+3]);
            float2v P01 = T0 * T1, P23 = T2 * T3, P = P01 * P23;
            float2v R; R.x = frcp(P.x); R.y = frcp(P.y);
            float2v n01 = nb2[r+0] * T1 + nb2[r+1] * T0;
            float2v n23 = nb2[r+2] * T3 + nb2[r+3] * T2;
            float2v num = n01 * P23 + n23 * P01;
            if (r & 4) Yb += num * R; else Ya += num * R;
        }
        float2v Yv = Ya + Yb;
        float y = Yv.x + Yv.y;
        y += __shfl_xor(y, 32, 64);
        if (g == 0) out[t * 32 + m] = base + y;

        // ---- tile t+1 from buffer B ----
        if (t + 1 < tend) {
            Frag bf2;
            bf2.d[0] = pack_bf2(b0v.x, b0v.y); bf2.d[1] = pack_bf2(b0v.z, b0v.w);
            bf2.d[2] = pack_bf2(b1v.x, b1v.y); bf2.d[3] = pack_bf2(b1v.z, b1v.w);
            if (t + 3 < tend) {            // refill B
                const float* zp = z + (size_t)((t + 3) * 32 + m) * 16 + g * 8;
                b0v = *(const floatx4*)zp; b1v = *(const floatx4*)(zp + 4);
            }
            floatx16 ac0 = __builtin_amdgcn_mfma_f32_32x32x16_bf16(af0.v, bf2.v, cinit0, 0, 0, 0);
            floatx16 ac1 = __builtin_amdgcn_mfma_f32_32x32x16_bf16(af1.v, bf2.v, cinit1, 0, 0, 0);

            float2v Yc = {0.0f, 0.0f}, Yd = {0.0f, 0.0f};
            #pragma unroll
            for (int r = 0; r < 16; r += 4) {
                float2v T0 = tpair(ac0[r+0], ac1[r+0]);
                float2v T1 = tpair(ac0[r+1], ac1[r+1]);
                float2v T2 = tpair(ac0[r+2], ac1[r+2]);
                float2v T3 = tpair(ac0[r+3], ac1[r+3]);
                float2v P01 = T0 * T1, P23 = T2 * T3, P = P01 * P23;
                float2v R; R.x = frcp(P.x); R.y = frcp(P.y);
                float2v n01 = nb2[r+0] * T1 + nb2[r+1] * T0;
                float2v n23 = nb2[r+2] * T3 + nb2[r+3] * T2;
                float2v num = n01 * P23 + n23 * P01;
                if (r & 4) Yd += num * R; else Yc += num * R;
            }
            float2v Yv2 = Yc + Yd;
            float y2 = Yv2.x + Yv2.y;
            y2 += __shfl_xor(y2, 32, 64);
            if (g == 0) out[(t + 1) * 32 + m] = base + y2;
        }
    }
}

extern "C" void kernel_launch(void* const* d_in, const int* in_sizes, int n_in,
                              void* d_out, int out_size, void* d_ws, size_t ws_size,
                              hipStream_t stream) {
    const float* z  = (const float*)d_in[0];
    const float* a0 = (const float*)d_in[1];
    const float* bk = (const float*)d_in[2];
    const float* ck = (const float*)d_in[3];
    const float* dk = (const float*)d_in[4];
    float* out = (float*)d_out;

    const int B      = in_sizes[0] / 16;   // z is [B,16]
    const int ntiles = B / 32;             // 32 batch rows per wave-tile

    dim3 grid(2048), block(256);           // 8192 waves, 8-tile chunk each
    hipLaunchKernelGGL(mave_kernel, grid, block, 0, stream,
                       z, a0, bk, ck, dk, out, ntiles);
}